// Round 1
// baseline (4003.662 us; speedup 1.0000x reference)
//
#include <hip/hip_runtime.h>
#include <math.h>

// Problem constants: B=1, C=256, H=96, W=96, N=8
#define CH   256
#define HH   96
#define WW   96
#define NN   8
#define HWSZ (HH*WW)   // 9216

// ---------------------------------------------------------------------------
// coord embedding sum: emb[c] = sum_n ( coord_diffs[n] . enc_w[c] + enc_b[c] )
__global__ void k_emb_sum(const float* __restrict__ cd,
                          const float* __restrict__ enc_w,
                          const float* __restrict__ enc_b,
                          float* __restrict__ emb)
{
    int c = threadIdx.x;            // 256 threads, 1 block
    float s = 0.f;
    for (int n = 0; n < NN; ++n) {
        float d = enc_b[c];
        #pragma unroll
        for (int j = 0; j < 4; ++j) d += cd[n*4 + j] * enc_w[c*4 + j];
        s += d;
    }
    emb[c] = s;
}

// ---------------------------------------------------------------------------
// transpose weights  w[O][CIN][9]  ->  wt[CIN*9][O]   (contiguous in o)
__global__ void k_transpose_w(const float* __restrict__ w,
                              float* __restrict__ wt, int O, int CIN)
{
    int idx = blockIdx.x * 256 + threadIdx.x;
    int total = O * CIN * 9;
    if (idx >= total) return;
    int o   = idx / (CIN * 9);
    int rem = idx % (CIN * 9);      // c*9 + k
    wt[rem * O + o] = w[idx];
}

// ---------------------------------------------------------------------------
// offset conv: concat([src_n, current]) (512ch) --3x3 pad1--> 18 ch
// grid: (36 tiles of 32x8, 8 neighbors), block 256 (one thread per pixel)
__global__ __launch_bounds__(256) void k_offset_conv(
    const float* __restrict__ cur, const float* __restrict__ nbr,
    const float* __restrict__ ow,  const float* __restrict__ ob,
    float* __restrict__ out)
{
    int n   = blockIdx.y;
    int t   = blockIdx.x;                 // 3 x-tiles(32) * 12 y-tiles(8)
    int tx0 = (t % 3) * 32;
    int ty0 = (t / 3) * 8;
    int tid = threadIdx.x;
    int lx  = tid % 32, ly = tid / 32;

    __shared__ float tile[8][10*34];

    float acc[18];
    #pragma unroll
    for (int o = 0; o < 18; ++o) acc[o] = ob[o];

    const float* srcn = nbr + (size_t)n * CH * HWSZ;

    for (int cc = 0; cc < 512; cc += 8) {
        for (int i = tid; i < 8*340; i += 256) {
            int ch  = i / 340, j = i % 340;
            int r   = j / 34,  col = j % 34;
            int gy  = ty0 - 1 + r, gx = tx0 - 1 + col;
            float v = 0.f;
            if (gy >= 0 && gy < HH && gx >= 0 && gx < WW) {
                int c = cc + ch;
                const float* base = (c < CH) ? (srcn + (size_t)c*HWSZ)
                                             : (cur  + (size_t)(c-CH)*HWSZ);
                v = base[gy*WW + gx];
            }
            tile[ch][j] = v;
        }
        __syncthreads();
        #pragma unroll 2
        for (int ci = 0; ci < 8; ++ci) {
            #pragma unroll
            for (int k = 0; k < 9; ++k) {
                int ky = k / 3, kx = k % 3;
                float v = tile[ci][(ly + ky)*34 + lx + kx];
                int wbase = (cc + ci)*9 + k;      // w[o][c][k] uniform index
                #pragma unroll
                for (int o = 0; o < 18; ++o)
                    acc[o] += ow[(size_t)o*512*9 + wbase] * v;
            }
        }
        __syncthreads();
    }
    int p = (ty0 + ly)*WW + tx0 + lx;
    #pragma unroll
    for (int o = 0; o < 18; ++o)
        out[((size_t)n*18 + o)*HWSZ + p] = acc[o];
}

// ---------------------------------------------------------------------------
// deformable conv 3x3: src_n (256ch) with offsets -> aligned (256ch)
// grid: (144 tiles of 8x8, 8 neighbors), block 256 = 4 waves.
// lane = pixel (8x8), wave og owns output channels [og*64, og*64+64)
__global__ __launch_bounds__(256) void k_deform_conv(
    const float* __restrict__ nbr, const float* __restrict__ offs,
    const float* __restrict__ wt /* [256*9][256] = (c,k,o) */,
    const float* __restrict__ ab, float* __restrict__ out)
{
    int n   = blockIdx.y;
    int t   = blockIdx.x;                  // 12 x 12 tiles of 8x8
    int tx0 = (t % 12) * 8, ty0 = (t / 12) * 8;
    int tid  = threadIdx.x;
    int lane = tid & 63;
    int og   = tid >> 6;
    int ogu  = __builtin_amdgcn_readfirstlane(og);

    __shared__ float S[8][9][64];          // samples: c-chunk, k, pixel
    __shared__ int   cy0[9*64];
    __shared__ int   cx0[9*64];
    __shared__ float cwy[9*64];
    __shared__ float cwx[9*64];

    // phase 1: bilinear coords for all (k, pixel)
    for (int i = tid; i < 9*64; i += 256) {
        int k = i / 64, p = i % 64;
        int y = ty0 + (p >> 3), x = tx0 + (p & 7);
        int pp = y*WW + x;
        float oy = offs[((size_t)n*18 + 2*k    )*HWSZ + pp];
        float ox = offs[((size_t)n*18 + 2*k + 1)*HWSZ + pp];
        float py = (float)y + (float)(k/3 - 1) + oy;
        float px = (float)x + (float)(k%3 - 1) + ox;
        float y0f = floorf(py), x0f = floorf(px);
        cy0[i] = (int)y0f;  cx0[i] = (int)x0f;
        cwy[i] = py - y0f;  cwx[i] = px - x0f;
    }
    __syncthreads();

    float acc[64];
    #pragma unroll
    for (int o = 0; o < 64; ++o) acc[o] = 0.f;

    const float* srcn = nbr + (size_t)n * CH * HWSZ;

    for (int cc = 0; cc < CH; cc += 8) {
        // cooperative bilinear sampling of 8 channels x 9 taps x 64 pixels
        for (int i = tid; i < 8*9*64; i += 256) {
            int ci = i / 576;
            int r  = i % 576;               // k*64 + p
            int p  = r & 63;
            const float* sp = srcn + (size_t)(cc + ci)*HWSZ;
            int   y0 = cy0[r], x0 = cx0[r];
            float wy = cwy[r], wx = cwx[r];
            bool y0i = (y0 >= 0) && (y0 < HH);
            bool y1i = (y0 >= -1) && (y0 < HH-1);
            bool x0i = (x0 >= 0) && (x0 < WW);
            bool x1i = (x0 >= -1) && (x0 < WW-1);
            int yb = y0*WW;
            float v00 = (y0i && x0i) ? sp[yb + x0]          : 0.f;
            float v01 = (y0i && x1i) ? sp[yb + x0 + 1]      : 0.f;
            float v10 = (y1i && x0i) ? sp[yb + WW + x0]     : 0.f;
            float v11 = (y1i && x1i) ? sp[yb + WW + x0 + 1] : 0.f;
            S[ci][r / 64][p] = (v00*(1.f-wy) + v10*wy)*(1.f-wx)
                             + (v01*(1.f-wy) + v11*wy)*wx;
        }
        __syncthreads();
        #pragma unroll 2
        for (int ci = 0; ci < 8; ++ci) {
            #pragma unroll
            for (int k = 0; k < 9; ++k) {
                float s = S[ci][k][lane];
                const float* wrow = wt + ((size_t)(cc+ci)*9 + k)*CH + ogu*64;
                #pragma unroll
                for (int o = 0; o < 64; ++o)
                    acc[o] += wrow[o] * s;       // wrow uniform -> s_load
            }
        }
        __syncthreads();
    }
    int p = (ty0 + (lane >> 3))*WW + tx0 + (lane & 7);
    #pragma unroll
    for (int o = 0; o < 64; ++o) {
        int oo = ogu*64 + o;
        out[((size_t)n*CH + oo)*HWSZ + p] = acc[o] + ab[oo];
    }
}

// ---------------------------------------------------------------------------
// gate: concat([current, aligned_n]) --3x3 pad1--> 128 -> relu -> 1x1 -> sigmoid
// grid: (144 tiles of 8x8, 8 neighbors), block 256 = 4 waves; wave og owns 32 ch
__global__ __launch_bounds__(256) void k_gate_conv(
    const float* __restrict__ cur, const float* __restrict__ alig,
    const float* __restrict__ g1t /* [512*9][128] */,
    const float* __restrict__ g1b,
    const float* __restrict__ g2w, const float* __restrict__ g2b,
    float* __restrict__ gout)
{
    int n   = blockIdx.y;
    int t   = blockIdx.x;
    int tx0 = (t % 12) * 8, ty0 = (t / 12) * 8;
    int tid  = threadIdx.x;
    int lane = tid & 63;
    int og   = tid >> 6;
    int ogu  = __builtin_amdgcn_readfirstlane(og);

    __shared__ float tile[8][100];
    __shared__ float partial[4][64];

    float acc[32];
    #pragma unroll
    for (int o = 0; o < 32; ++o) acc[o] = 0.f;

    const float* alin = alig + (size_t)n * CH * HWSZ;
    int px_ = lane & 7, py_ = lane >> 3;

    for (int cc = 0; cc < 512; cc += 8) {
        for (int i = tid; i < 800; i += 256) {
            int ch = i / 100, j = i % 100;
            int r  = j / 10,  col = j % 10;
            int gy = ty0 - 1 + r, gx = tx0 - 1 + col;
            float v = 0.f;
            if (gy >= 0 && gy < HH && gx >= 0 && gx < WW) {
                int c = cc + ch;
                const float* base = (c < CH) ? (cur  + (size_t)c*HWSZ)
                                             : (alin + (size_t)(c-CH)*HWSZ);
                v = base[gy*WW + gx];
            }
            tile[ch][j] = v;
        }
        __syncthreads();
        #pragma unroll 2
        for (int ci = 0; ci < 8; ++ci) {
            #pragma unroll
            for (int k = 0; k < 9; ++k) {
                int ky = k / 3, kx = k % 3;
                float v = tile[ci][(py_ + ky)*10 + px_ + kx];
                const float* wrow = g1t + ((size_t)(cc+ci)*9 + k)*128 + ogu*32;
                #pragma unroll
                for (int o = 0; o < 32; ++o)
                    acc[o] += wrow[o] * v;
            }
        }
        __syncthreads();
    }
    float part = 0.f;
    #pragma unroll
    for (int o = 0; o < 32; ++o) {
        float r = acc[o] + g1b[ogu*32 + o];
        r = fmaxf(r, 0.f);
        part += r * g2w[ogu*32 + o];
    }
    partial[og][lane] = part;
    __syncthreads();
    if (tid < 64) {
        float s = partial[0][tid] + partial[1][tid]
                + partial[2][tid] + partial[3][tid] + g2b[0];
        float g = 1.f / (1.f + expf(-s));
        int p = (ty0 + (tid >> 3))*WW + tx0 + (tid & 7);
        gout[(size_t)n*HWSZ + p] = g;
    }
}

// ---------------------------------------------------------------------------
// final fusion: softmax over N of g, weighted sum of aligned, +emb, residual
__global__ void k_fuse(const float* __restrict__ cur,
                       const float* __restrict__ alig,
                       const float* __restrict__ g,
                       const float* __restrict__ emb,
                       float* __restrict__ out)
{
    int idx = blockIdx.x * 256 + threadIdx.x;     // c*HWSZ + p
    if (idx >= CH * HWSZ) return;
    int c = idx / HWSZ, p = idx % HWSZ;
    float e[NN]; float m = -1e30f;
    #pragma unroll
    for (int n = 0; n < NN; ++n) { e[n] = g[n*HWSZ + p]; m = fmaxf(m, e[n]); }
    float se = 0.f;
    #pragma unroll
    for (int n = 0; n < NN; ++n) { e[n] = expf(e[n] - m); se += e[n]; }
    float inv = 1.f / se;
    float s = 0.f;
    #pragma unroll
    for (int n = 0; n < NN; ++n)
        s += alig[((size_t)n*CH + c)*HWSZ + p] * e[n];
    s = s * inv + emb[c];
    out[idx] = cur[idx] + 0.5f * s;
}

// ---------------------------------------------------------------------------
extern "C" void kernel_launch(void* const* d_in, const int* in_sizes, int n_in,
                              void* d_out, int out_size, void* d_ws, size_t ws_size,
                              hipStream_t stream)
{
    const float* cur = (const float*)d_in[0];   // [1,256,96,96]
    const float* nbr = (const float*)d_in[1];   // [8,1,256,96,96]
    const float* cd  = (const float*)d_in[2];   // [8,4]
    const float* aw  = (const float*)d_in[3];   // [256,256,3,3]
    const float* ab  = (const float*)d_in[4];   // [256]
    const float* ow  = (const float*)d_in[5];   // [18,512,3,3]
    const float* ob  = (const float*)d_in[6];   // [18]
    const float* g1w = (const float*)d_in[7];   // [128,512,3,3]
    const float* g1b = (const float*)d_in[8];   // [128]
    const float* g2w = (const float*)d_in[9];   // [1,128,1,1]
    const float* g2b = (const float*)d_in[10];  // [1]
    const float* ew  = (const float*)d_in[11];  // [256,4]
    const float* eb  = (const float*)d_in[12];  // [256]
    float* out = (float*)d_out;
    float* ws  = (float*)d_ws;

    float* offs = ws;                       // 8*18*9216      = 1,327,104
    float* alig = offs + 1327104;           // 8*256*9216     = 18,874,368
    float* gbuf = alig + 18874368;          // 8*9216         = 73,728
    float* emb  = gbuf + 73728;             // 256
    float* wtA  = emb  + 256;               // 256*9*256      = 589,824
    float* wtG  = wtA  + 589824;            // 512*9*128      = 589,824

    k_emb_sum<<<dim3(1), dim3(256), 0, stream>>>(cd, ew, eb, emb);
    k_transpose_w<<<dim3((589824 + 255) / 256), dim3(256), 0, stream>>>(aw, wtA, 256, 256);
    k_transpose_w<<<dim3((589824 + 255) / 256), dim3(256), 0, stream>>>(g1w, wtG, 128, 512);
    k_offset_conv<<<dim3(36, 8), dim3(256), 0, stream>>>(cur, nbr, ow, ob, offs);
    k_deform_conv<<<dim3(144, 8), dim3(256), 0, stream>>>(nbr, offs, wtA, ab, alig);
    k_gate_conv<<<dim3(144, 8), dim3(256), 0, stream>>>(cur, alig, wtG, g1b, g2w, g2b, gbuf);
    k_fuse<<<dim3((CH*HWSZ + 255) / 256), dim3(256), 0, stream>>>(cur, alig, gbuf, emb, out);
}

// Round 2
// 2129.325 us; speedup vs baseline: 1.8802x; 1.8802x over previous
//
#include <hip/hip_runtime.h>
#include <math.h>

// Problem constants: B=1, C=256, H=96, W=96, N=8
#define CH   256
#define HH   96
#define WW   96
#define NN   8
#define HWSZ (HH*WW)   // 9216

typedef short bf16x8 __attribute__((ext_vector_type(8)));
typedef float f32x4  __attribute__((ext_vector_type(4)));

__device__ inline unsigned short f2bf(float f) {
    union { float f; unsigned u; } v; v.f = f;
    unsigned r = v.u + 0x7FFF + ((v.u >> 16) & 1);   // RNE
    return (unsigned short)(r >> 16);
}

// ---------------------------------------------------------------------------
// coord embedding sum: emb[c] = sum_n ( coord_diffs[n] . enc_w[c] + enc_b[c] )
__global__ void k_emb_sum(const float* __restrict__ cd,
                          const float* __restrict__ enc_w,
                          const float* __restrict__ enc_b,
                          float* __restrict__ emb)
{
    int c = threadIdx.x;            // 256 threads, 1 block
    float s = 0.f;
    for (int n = 0; n < NN; ++n) {
        float d = enc_b[c];
        #pragma unroll
        for (int j = 0; j < 4; ++j) d += cd[n*4 + j] * enc_w[c*4 + j];
        s += d;
    }
    emb[c] = s;
}

// ---------------------------------------------------------------------------
// pack conv weights w[O][CIN][3][3] (fp32, OIHW) into bf16 A-fragment layout:
// K = tap*CIN + c  (tap-major).  Wp[o>>4][K>>5][lane][8] where
// lane = ((K&31)>>3)*16 + (o&15), j = K&7.  Rows o in [O, O_pad) are zero.
__global__ void k_pack_w(const float* __restrict__ w, unsigned short* __restrict__ wp,
                         int O, int O_pad, int CIN)
{
    int idx = blockIdx.x * 256 + threadIdx.x;
    int total = O_pad * CIN * 9;
    if (idx >= total) return;
    int o = idx / (CIN * 9);
    int K = idx % (CIN * 9);
    int tap = K / CIN, c = K % CIN;
    float v = (o < O) ? w[((size_t)o * CIN + c) * 9 + tap] : 0.f;
    int NKC = (CIN * 9) >> 5;
    int kc = K >> 5, kl = K & 31;
    int lane = (kl >> 3) * 16 + (o & 15);
    size_t dstp = (((size_t)(o >> 4) * NKC + kc) * 64 + lane) * 8 + (kl & 7);
    wp[dstp] = f2bf(v);
}

// ---------------------------------------------------------------------------
// generic 3x3 pad1 conv on concat(in0_n, in1_n) (512 in-ch) via bf16 MFMA.
// grid (144 tiles of 8x8 px, 8 neighbors), block 256 = 4 waves.
// MTW = mtiles (16 oc) per wave.  EPI: 0 = store fp32 planes (first 18 oc),
// 1 = gate epilogue (relu -> 1x1 conv -> sigmoid -> [n][HW]).
template<int MTW, int EPI>
__global__ __launch_bounds__(256) void k_conv_mfma(
    const float* __restrict__ in0, long s0,
    const float* __restrict__ in1, long s1,
    const unsigned short* __restrict__ Wp,
    const float* __restrict__ b1,
    const float* __restrict__ g2w,
    const float* __restrict__ g2b,
    float* __restrict__ out)
{
    constexpr int NKC = 144;                // K = 512*9 = 4608, chunks of 32
    int n = blockIdx.y;
    int t = blockIdx.x;
    int tx0 = (t % 12) * 8, ty0 = (t / 12) * 8;
    int tid = threadIdx.x;
    int lane = tid & 63;
    int w = tid >> 6;

    __shared__ unsigned short SB[2048];     // 32 k x 64 px, fragment layout
    __shared__ float partial[4][64];

    f32x4 acc[MTW][4];
    #pragma unroll
    for (int mt = 0; mt < MTW; ++mt)
        #pragma unroll
        for (int nf = 0; nf < 4; ++nf)
            acc[mt][nf] = (f32x4){0.f, 0.f, 0.f, 0.f};

    const float* p0 = in0 + (size_t)n * s0;
    const float* p1 = in1 + (size_t)n * s1;

    int px = tid & 63, kgrp = tid >> 6;
    int row = px >> 3, col = px & 7;
    int dst = ((px >> 4) * 4 + kgrp) * 128 + (px & 15) * 8;

    auto produce = [&](int kc) -> int4 {
        int tap = kc >> 4;
        int c0 = (kc & 15) * 32 + kgrp * 8;
        int dy = tap / 3 - 1, dx = tap % 3 - 1;
        int y = ty0 + row + dy, x = tx0 + col + dx;
        bool valid = (y >= 0) && (y < HH) && (x >= 0) && (x < WW);
        const float* plane = (c0 < CH) ? (p0 + (size_t)c0 * HWSZ)
                                       : (p1 + (size_t)(c0 - CH) * HWSZ);
        int sp = y * WW + x;
        unsigned u[4];
        #pragma unroll
        for (int jj = 0; jj < 4; ++jj) {
            float f0 = valid ? plane[(size_t)(2*jj    ) * HWSZ + sp] : 0.f;
            float f1 = valid ? plane[(size_t)(2*jj + 1) * HWSZ + sp] : 0.f;
            u[jj] = (unsigned)f2bf(f0) | ((unsigned)f2bf(f1) << 16);
        }
        return make_int4((int)u[0], (int)u[1], (int)u[2], (int)u[3]);
    };
    auto loadA = [&](int kc, bf16x8* a) {
        #pragma unroll
        for (int mt = 0; mt < MTW; ++mt) {
            size_t off = (((size_t)(w * MTW + mt) * NKC + kc) * 64 + lane) * 8;
            a[mt] = *reinterpret_cast<const bf16x8*>(Wp + off);
        }
    };

    int4 vpk = produce(0);
    bf16x8 apf[MTW]; loadA(0, apf);

    for (int kc = 0; kc < NKC; ++kc) {
        __syncthreads();                      // consumers of kc-1 done
        *reinterpret_cast<int4*>(&SB[dst]) = vpk;
        bf16x8 acur[MTW];
        #pragma unroll
        for (int mt = 0; mt < MTW; ++mt) acur[mt] = apf[mt];
        __syncthreads();                      // SB visible
        int kn = (kc + 1 < NKC) ? kc + 1 : NKC - 1;
        vpk = produce(kn);                    // issue next loads early (T14)
        loadA(kn, apf);
        #pragma unroll
        for (int nf = 0; nf < 4; ++nf) {
            bf16x8 b = *reinterpret_cast<const bf16x8*>(
                &SB[(nf * 4 + (lane >> 4)) * 128 + (lane & 15) * 8]);
            #pragma unroll
            for (int mt = 0; mt < MTW; ++mt)
                acc[mt][nf] = __builtin_amdgcn_mfma_f32_16x16x32_bf16(
                                  acur[mt], b, acc[mt][nf], 0, 0, 0);
        }
    }

    if (EPI == 0) {
        // store planes: o = w*16 + (lane>>4)*4 + r, keep o < 18
        #pragma unroll
        for (int nf = 0; nf < 4; ++nf) {
            int pxl = nf * 16 + (lane & 15);
            int gp = (ty0 + (pxl >> 3)) * WW + tx0 + (pxl & 7);
            int o_base = w * 16 + ((lane >> 4) << 2);
            #pragma unroll
            for (int r = 0; r < 4; ++r) {
                int o = o_base + r;
                if (o < 18)
                    out[((size_t)n * 18 + o) * HWSZ + gp] = acc[0][nf][r] + b1[o];
            }
        }
    } else {
        float part[4] = {0.f, 0.f, 0.f, 0.f};
        #pragma unroll
        for (int nf = 0; nf < 4; ++nf)
            #pragma unroll
            for (int mt = 0; mt < MTW; ++mt) {
                int o_base = (w * MTW + mt) * 16 + ((lane >> 4) << 2);
                #pragma unroll
                for (int r = 0; r < 4; ++r) {
                    int o = o_base + r;
                    float v = fmaxf(acc[mt][nf][r] + b1[o], 0.f);
                    part[nf] += v * g2w[o];
                }
            }
        #pragma unroll
        for (int nf = 0; nf < 4; ++nf) {
            part[nf] += __shfl_xor(part[nf], 16, 64);
            part[nf] += __shfl_xor(part[nf], 32, 64);
        }
        if ((lane >> 4) == 0) {
            #pragma unroll
            for (int nf = 0; nf < 4; ++nf)
                partial[w][nf * 16 + lane] = part[nf];
        }
        __syncthreads();
        if (tid < 64) {
            float s = partial[0][tid] + partial[1][tid]
                    + partial[2][tid] + partial[3][tid] + g2b[0];
            float g = 1.f / (1.f + expf(-s));
            int gp = (ty0 + (tid >> 3)) * WW + tx0 + (tid & 7);
            out[(size_t)n * HWSZ + gp] = g;
        }
    }
}

// ---------------------------------------------------------------------------
// deformable 3x3 conv via bf16 MFMA: src_n (256ch) + offsets -> aligned (256ch)
// grid (144 tiles, 8 neighbors), block 256 = 4 waves, each wave 64 oc x 64 px.
__global__ __launch_bounds__(256) void k_deform_mfma(
    const float* __restrict__ nbr, const float* __restrict__ offs,
    const unsigned short* __restrict__ Wp, const float* __restrict__ ab,
    float* __restrict__ out)
{
    constexpr int NKC = 72;                 // K = 256*9 = 2304, chunks of 32
    int n = blockIdx.y;
    int t = blockIdx.x;
    int tx0 = (t % 12) * 8, ty0 = (t / 12) * 8;
    int tid = threadIdx.x, lane = tid & 63, w = tid >> 6;

    __shared__ unsigned short SB[2048];
    __shared__ int   cy[576];
    __shared__ int   cx[576];
    __shared__ float cwy[576];
    __shared__ float cwx[576];

    const float* srcn = nbr + (size_t)n * CH * HWSZ;

    // bilinear coords for 9 taps x 64 px
    for (int i = tid; i < 576; i += 256) {
        int k = i / 64, p = i % 64;
        int y = ty0 + (p >> 3), x = tx0 + (p & 7);
        int pp = y * WW + x;
        float oy = offs[((size_t)n * 18 + 2 * k    ) * HWSZ + pp];
        float ox = offs[((size_t)n * 18 + 2 * k + 1) * HWSZ + pp];
        float py = (float)y + (float)(k / 3 - 1) + oy;
        float pxx = (float)x + (float)(k % 3 - 1) + ox;
        float y0f = floorf(py), x0f = floorf(pxx);
        cy[i] = (int)y0f; cx[i] = (int)x0f;
        cwy[i] = py - y0f; cwx[i] = pxx - x0f;
    }
    __syncthreads();

    f32x4 acc[4][4];
    #pragma unroll
    for (int mt = 0; mt < 4; ++mt)
        #pragma unroll
        for (int nf = 0; nf < 4; ++nf)
            acc[mt][nf] = (f32x4){0.f, 0.f, 0.f, 0.f};

    int px = tid & 63, kgrp = tid >> 6;
    int dst = ((px >> 4) * 4 + kgrp) * 128 + (px & 15) * 8;

    auto produce = [&](int kc) -> int4 {
        int tap = kc >> 3;
        int c0 = (kc & 7) * 32 + kgrp * 8;
        int r = tap * 64 + px;
        int y0 = cy[r], x0 = cx[r];
        float wy = cwy[r], wx = cwx[r];
        bool y0i = (y0 >= 0) & (y0 < HH);
        bool y1i = (y0 >= -1) & (y0 < HH - 1);
        bool x0i = (x0 >= 0) & (x0 < WW);
        bool x1i = (x0 >= -1) & (x0 < WW - 1);
        float w00 = (1.f - wy) * (1.f - wx), w01 = (1.f - wy) * wx;
        float w10 = wy * (1.f - wx),         w11 = wy * wx;
        int a00 = y0 * WW + x0;
        const float* sp = srcn + (size_t)c0 * HWSZ;
        unsigned u[4];
        #pragma unroll
        for (int jj = 0; jj < 8; ++jj) {
            const float* s2 = sp + (size_t)jj * HWSZ;
            float v00 = (y0i && x0i) ? s2[a00]          : 0.f;
            float v01 = (y0i && x1i) ? s2[a00 + 1]      : 0.f;
            float v10 = (y1i && x0i) ? s2[a00 + WW]     : 0.f;
            float v11 = (y1i && x1i) ? s2[a00 + WW + 1] : 0.f;
            float sv = v00 * w00 + v01 * w01 + v10 * w10 + v11 * w11;
            unsigned short h = f2bf(sv);
            if (jj & 1) u[jj >> 1] |= ((unsigned)h << 16);
            else        u[jj >> 1]  = h;
        }
        return make_int4((int)u[0], (int)u[1], (int)u[2], (int)u[3]);
    };
    auto loadA = [&](int kc, bf16x8* a) {
        #pragma unroll
        for (int mt = 0; mt < 4; ++mt) {
            size_t off = (((size_t)(w * 4 + mt) * NKC + kc) * 64 + lane) * 8;
            a[mt] = *reinterpret_cast<const bf16x8*>(Wp + off);
        }
    };

    int4 vpk = produce(0);
    bf16x8 apf[4]; loadA(0, apf);

    for (int kc = 0; kc < NKC; ++kc) {
        __syncthreads();
        *reinterpret_cast<int4*>(&SB[dst]) = vpk;
        bf16x8 acur[4];
        #pragma unroll
        for (int mt = 0; mt < 4; ++mt) acur[mt] = apf[mt];
        __syncthreads();
        int kn = (kc + 1 < NKC) ? kc + 1 : NKC - 1;
        vpk = produce(kn);
        loadA(kn, apf);
        #pragma unroll
        for (int nf = 0; nf < 4; ++nf) {
            bf16x8 b = *reinterpret_cast<const bf16x8*>(
                &SB[(nf * 4 + (lane >> 4)) * 128 + (lane & 15) * 8]);
            #pragma unroll
            for (int mt = 0; mt < 4; ++mt)
                acc[mt][nf] = __builtin_amdgcn_mfma_f32_16x16x32_bf16(
                                  acur[mt], b, acc[mt][nf], 0, 0, 0);
        }
    }

    #pragma unroll
    for (int nf = 0; nf < 4; ++nf) {
        int pxl = nf * 16 + (lane & 15);
        int gp = (ty0 + (pxl >> 3)) * WW + tx0 + (pxl & 7);
        #pragma unroll
        for (int mt = 0; mt < 4; ++mt) {
            int o_base = (w * 4 + mt) * 16 + ((lane >> 4) << 2);
            #pragma unroll
            for (int r = 0; r < 4; ++r) {
                int o = o_base + r;
                out[((size_t)n * CH + o) * HWSZ + gp] = acc[mt][nf][r] + ab[o];
            }
        }
    }
}

// ---------------------------------------------------------------------------
// final fusion: softmax over N of g, weighted sum of aligned, +emb, residual
__global__ void k_fuse(const float* __restrict__ cur,
                       const float* __restrict__ alig,
                       const float* __restrict__ g,
                       const float* __restrict__ emb,
                       float* __restrict__ out)
{
    int idx = blockIdx.x * 256 + threadIdx.x;     // c*HWSZ + p
    if (idx >= CH * HWSZ) return;
    int c = idx / HWSZ, p = idx % HWSZ;
    float e[NN]; float m = -1e30f;
    #pragma unroll
    for (int n = 0; n < NN; ++n) { e[n] = g[n*HWSZ + p]; m = fmaxf(m, e[n]); }
    float se = 0.f;
    #pragma unroll
    for (int n = 0; n < NN; ++n) { e[n] = expf(e[n] - m); se += e[n]; }
    float inv = 1.f / se;
    float s = 0.f;
    #pragma unroll
    for (int n = 0; n < NN; ++n)
        s += alig[((size_t)n*CH + c)*HWSZ + p] * e[n];
    s = s * inv + emb[c];
    out[idx] = cur[idx] + 0.5f * s;
}

// ---------------------------------------------------------------------------
extern "C" void kernel_launch(void* const* d_in, const int* in_sizes, int n_in,
                              void* d_out, int out_size, void* d_ws, size_t ws_size,
                              hipStream_t stream)
{
    const float* cur = (const float*)d_in[0];   // [1,256,96,96]
    const float* nbr = (const float*)d_in[1];   // [8,1,256,96,96]
    const float* cd  = (const float*)d_in[2];   // [8,4]
    const float* aw  = (const float*)d_in[3];   // [256,256,3,3]
    const float* ab  = (const float*)d_in[4];   // [256]
    const float* ow  = (const float*)d_in[5];   // [18,512,3,3]
    const float* ob  = (const float*)d_in[6];   // [18]
    const float* g1w = (const float*)d_in[7];   // [128,512,3,3]
    const float* g1b = (const float*)d_in[8];   // [128]
    const float* g2w = (const float*)d_in[9];   // [1,128,1,1]
    const float* g2b = (const float*)d_in[10];  // [1]
    const float* ew  = (const float*)d_in[11];  // [256,4]
    const float* eb  = (const float*)d_in[12];  // [256]
    float* out = (float*)d_out;
    float* ws  = (float*)d_ws;

    float* offs = ws;                       // 8*18*9216      = 1,327,104 f
    float* alig = offs + 1327104;           // 8*256*9216     = 18,874,368 f
    float* gbuf = alig + 18874368;          // 8*9216         = 73,728 f
    float* emb  = gbuf + 73728;             // 256 f
    unsigned short* wpO = (unsigned short*)(emb + 256);   // 64mt?: 4*144*64*8 = 294,912 u16
    unsigned short* wpG = wpO + 294912;                   // 8*144*64*8 = 589,824 u16
    unsigned short* wpA = wpG + 589824;                   // 16*72*64*8 = 589,824 u16

    k_emb_sum<<<dim3(1), dim3(256), 0, stream>>>(cd, ew, eb, emb);
    k_pack_w<<<dim3((64*4608 + 255)/256), dim3(256), 0, stream>>>(ow, wpO, 18, 64, 512);
    k_pack_w<<<dim3((128*4608 + 255)/256), dim3(256), 0, stream>>>(g1w, wpG, 128, 128, 512);
    k_pack_w<<<dim3((256*2304 + 255)/256), dim3(256), 0, stream>>>(aw, wpA, 256, 256, 256);

    // offset conv: concat(nbr_n, cur) -> 18 ch (padded to 64)
    k_conv_mfma<1, 0><<<dim3(144, 8), dim3(256), 0, stream>>>(
        nbr, (long)CH*HWSZ, cur, 0L, wpO, ob, nullptr, nullptr, offs);
    // deformable conv
    k_deform_mfma<<<dim3(144, 8), dim3(256), 0, stream>>>(nbr, offs, wpA, ab, alig);
    // gate: concat(cur, aligned_n) -> 128 -> relu -> 1x1 -> sigmoid
    k_conv_mfma<2, 1><<<dim3(144, 8), dim3(256), 0, stream>>>(
        cur, 0L, alig, (long)CH*HWSZ, wpG, g1b, g2w, g2b, gbuf);
    // softmax + fuse + residual
    k_fuse<<<dim3((CH*HWSZ + 255)/256), dim3(256), 0, stream>>>(cur, alig, gbuf, emb, out);
}

// Round 3
// 1496.800 us; speedup vs baseline: 2.6748x; 1.4226x over previous
//
#include <hip/hip_runtime.h>
#include <math.h>

// Problem constants: B=1, C=256, H=96, W=96, N=8
#define CH   256
#define HH   96
#define WW   96
#define NN   8
#define HWSZ (HH*WW)   // 9216

typedef unsigned short u16;
typedef unsigned int   u32;
typedef short bf16x8 __attribute__((ext_vector_type(8)));
typedef float f32x4  __attribute__((ext_vector_type(4)));

__device__ inline u16 f2bf(float f) {
    union { float f; unsigned u; } v; v.f = f;
    unsigned r = v.u + 0x7FFF + ((v.u >> 16) & 1);   // RNE
    return (u16)(r >> 16);
}
__device__ inline float bf2f(u16 h) {
    union { unsigned u; float f; } v; v.u = (unsigned)h << 16; return v.f;
}

// ---------------------------------------------------------------------------
__global__ void k_emb_sum(const float* __restrict__ cd,
                          const float* __restrict__ enc_w,
                          const float* __restrict__ enc_b,
                          float* __restrict__ emb)
{
    int c = threadIdx.x;
    float s = 0.f;
    for (int n = 0; n < NN; ++n) {
        float d = enc_b[c];
        #pragma unroll
        for (int j = 0; j < 4; ++j) d += cd[n*4 + j] * enc_w[c*4 + j];
        s += d;
    }
    emb[c] = s;
}

// ---------------------------------------------------------------------------
// fp32 -> bf16 plane conversion, vectorized (float4 -> ushort4)
__global__ void k_tobf16(const float* __restrict__ in, u16* __restrict__ out, int n4)
{
    int i = blockIdx.x * 256 + threadIdx.x;
    if (i >= n4) return;
    float4 v = reinterpret_cast<const float4*>(in)[i];
    ushort4 h;
    h.x = f2bf(v.x); h.y = f2bf(v.y); h.z = f2bf(v.z); h.w = f2bf(v.w);
    reinterpret_cast<ushort4*>(out)[i] = h;
}

// ---------------------------------------------------------------------------
// pack conv weights w[O][CIN][3][3] (fp32, OIHW) into bf16 A-fragment layout.
// K = tap*CIN + c (tap-major); kc = K>>5 = tap*(CIN/32) + (c>>5).
// Wp[o>>4][kc][lane][8], lane = ((K&31)>>3)*16 + (o&15), j = K&7.
__global__ void k_pack_w(const float* __restrict__ w, u16* __restrict__ wp,
                         int O, int O_pad, int CIN)
{
    int idx = blockIdx.x * 256 + threadIdx.x;
    int total = O_pad * CIN * 9;
    if (idx >= total) return;
    int o = idx / (CIN * 9);
    int K = idx % (CIN * 9);
    int tap = K / CIN, c = K % CIN;
    float v = (o < O) ? w[((size_t)o * CIN + c) * 9 + tap] : 0.f;
    int NKC = (CIN * 9) >> 5;
    int kc = K >> 5, kl = K & 31;
    int lane = (kl >> 3) * 16 + (o & 15);
    size_t dstp = (((size_t)(o >> 4) * NKC + kc) * 64 + lane) * 8 + (kl & 7);
    wp[dstp] = f2bf(v);
}

// ---------------------------------------------------------------------------
// stage one 32-channel halo tile (10 rows x 34 cols) into LDS [340 px][40 u16]
template<bool ISF32>
__device__ inline void stage_tile(const void* __restrict__ base, int tid,
                                  int ty0, int tx0, u16* __restrict__ SB)
{
    for (int i = tid; i < 2720; i += 512) {
        int q  = i / 340;            // channel quad 0..7
        int ph = i - q * 340;        // halo px 0..339
        int r  = ph / 34;
        int col = ph - r * 34;
        int y = ty0 - 1 + r, x = tx0 - 1 + col;
        bool v = ((unsigned)y < (unsigned)HH) && ((unsigned)x < (unsigned)WW);
        int sp = y * WW + x;
        unsigned long long pk = 0;
        #pragma unroll
        for (int j = 0; j < 4; ++j) {
            u16 h;
            if (ISF32) {
                float f = v ? ((const float*)base)[(size_t)(q*4+j)*HWSZ + sp] : 0.f;
                h = f2bf(f);
            } else {
                h = v ? ((const u16*)base)[(size_t)(q*4+j)*HWSZ + sp] : (u16)0;
            }
            pk |= (unsigned long long)h << (16*j);
        }
        *reinterpret_cast<unsigned long long*>(&SB[ph*40 + q*4]) = pk;
    }
}

// ---------------------------------------------------------------------------
// shift-conv 3x3 pad1 on concat(in0_n, in1_n) (512 in-ch) via bf16 MFMA.
// tile 8 rows x 32 cols (256 px), grid (36, 8), block 512 = 8 waves.
// wave w: mh = w>>2 (m-half), pg = w&3 (64-px group). MTW mtiles per wave.
// EPI 0: store fp32 planes (o < 18) -> offs.  EPI 1: gate epilogue -> gbuf.
template<int MTW, int EPI, bool F0, bool F1>
__global__ __launch_bounds__(512) void k_conv_shift(
    const void* __restrict__ in0, long s0,
    const void* __restrict__ in1, long s1,
    const u16* __restrict__ Wp, const float* __restrict__ b1,
    const float* __restrict__ g2w, const float* __restrict__ g2b,
    float* __restrict__ out)
{
    constexpr int NKC = 144, NCC = 16;
    int n = blockIdx.y, t = blockIdx.x;
    int tx0 = (t % 3) * 32, ty0 = (t / 3) * 8;
    int tid = threadIdx.x, lane = tid & 63, w = tid >> 6;
    int mh = w >> 2, pg = w & 3;
    int colq = lane >> 4;

    __shared__ __align__(16) u16 SB[340*40];
    __shared__ float gpart[8][64];

    f32x4 acc[MTW][4];
    #pragma unroll
    for (int mt = 0; mt < MTW; ++mt)
        #pragma unroll
        for (int nf = 0; nf < 4; ++nf)
            acc[mt][nf] = (f32x4){0.f,0.f,0.f,0.f};

    int bidx[4];
    #pragma unroll
    for (int nf = 0; nf < 4; ++nf) {
        int px = pg*64 + nf*16 + (lane & 15);
        int row = px >> 5, col = px & 31;
        bidx[nf] = ((row+1)*34 + (col+1))*40 + colq*8;
    }

    for (int cc = 0; cc < NCC; ++cc) {
        if (cc < 8)
            stage_tile<F0>((const void*)((const char*)in0
                + ((size_t)n*s0 + (size_t)cc*32*HWSZ) * (F0 ? 4 : 2)),
                tid, ty0, tx0, SB);
        else
            stage_tile<F1>((const void*)((const char*)in1
                + ((size_t)n*s1 + (size_t)(cc-8)*32*HWSZ) * (F1 ? 4 : 2)),
                tid, ty0, tx0, SB);
        __syncthreads();
        #pragma unroll
        for (int tap = 0; tap < 9; ++tap) {
            int kc = tap*NCC + cc;
            bf16x8 a[MTW];
            #pragma unroll
            for (int mt = 0; mt < MTW; ++mt)
                a[mt] = *reinterpret_cast<const bf16x8*>(
                    Wp + (((size_t)(mh*MTW+mt)*NKC + kc)*64 + lane)*8);
            const int dy = tap/3 - 1, dx = tap%3 - 1;
            #pragma unroll
            for (int nf = 0; nf < 4; ++nf) {
                bf16x8 b = *reinterpret_cast<const bf16x8*>(
                    &SB[bidx[nf] + (dy*34 + dx)*40]);
                #pragma unroll
                for (int mt = 0; mt < MTW; ++mt)
                    acc[mt][nf] = __builtin_amdgcn_mfma_f32_16x16x32_bf16(
                                      a[mt], b, acc[mt][nf], 0, 0, 0);
            }
        }
        __syncthreads();
    }

    if (EPI == 0) {
        #pragma unroll
        for (int nf = 0; nf < 4; ++nf) {
            int px = pg*64 + nf*16 + (lane & 15);
            int gp = (ty0 + (px>>5))*WW + tx0 + (px & 31);
            #pragma unroll
            for (int mt = 0; mt < MTW; ++mt) {
                int o_base = (mh*MTW+mt)*16 + colq*4;
                #pragma unroll
                for (int r = 0; r < 4; ++r) {
                    int o = o_base + r;
                    if (o < 18)
                        out[((size_t)n*18 + o)*HWSZ + gp] = acc[mt][nf][r] + b1[o];
                }
            }
        }
    } else {
        float part[4];
        #pragma unroll
        for (int nf = 0; nf < 4; ++nf) {
            float s = 0.f;
            #pragma unroll
            for (int mt = 0; mt < MTW; ++mt) {
                int o_base = (mh*MTW+mt)*16 + colq*4;
                #pragma unroll
                for (int r = 0; r < 4; ++r) {
                    int o = o_base + r;
                    float vv = fmaxf(acc[mt][nf][r] + b1[o], 0.f);
                    s += vv * g2w[o];
                }
            }
            part[nf] = s;
        }
        #pragma unroll
        for (int nf = 0; nf < 4; ++nf) {
            part[nf] += __shfl_xor(part[nf], 16, 64);
            part[nf] += __shfl_xor(part[nf], 32, 64);
        }
        if (lane < 16) {
            #pragma unroll
            for (int nf = 0; nf < 4; ++nf)
                gpart[w][nf*16 + lane] = part[nf];
        }
        __syncthreads();
        if (tid < 256) {
            int pxl = tid & 63, pgg = tid >> 6;
            float s = gpart[pgg][pxl] + gpart[4 + pgg][pxl] + g2b[0];
            float g = 1.f / (1.f + expf(-s));
            int px = pgg*64 + pxl;
            int gp = (ty0 + (px>>5))*WW + tx0 + (px & 31);
            out[(size_t)n*HWSZ + gp] = g;
        }
    }
}

// ---------------------------------------------------------------------------
// deformable 3x3 conv via bf16 MFMA, bf16 in/out.
// tile 4 rows x 32 cols (128 px), grid (72, 8), block 512 = 8 waves.
// wave w: mh = w>>1 (0..3, 64 oc each), pg = w&1 (64-px group).
__global__ __launch_bounds__(512) void k_deform_shift(
    const u16* __restrict__ nbrb, const float* __restrict__ offs,
    const u16* __restrict__ Wp, const float* __restrict__ ab,
    u16* __restrict__ alig)
{
    constexpr int NKC = 72;
    int n = blockIdx.y, t = blockIdx.x;
    int tx0 = (t % 3) * 32, ty0 = (t / 3) * 4;
    int tid = threadIdx.x, lane = tid & 63, w = tid >> 6;
    int mh = w >> 1, pg = w & 1;
    int colq = lane >> 4;

    __shared__ __align__(16) u16 SB[128*40];
    __shared__ u32   cpos[1152];
    __shared__ float cwy[1152];
    __shared__ float cwx[1152];

    const u16* src = nbrb + (size_t)n * CH * HWSZ;

    for (int i = tid; i < 1152; i += 512) {
        int tt = i >> 7, px = i & 127;
        int y = ty0 + (px>>5), x = tx0 + (px & 31);
        int pp = y*WW + x;
        float oy = offs[((size_t)n*18 + 2*tt    )*HWSZ + pp];
        float ox = offs[((size_t)n*18 + 2*tt + 1)*HWSZ + pp];
        float py  = (float)y + (float)(tt/3 - 1) + oy;
        float pxx = (float)x + (float)(tt%3 - 1) + ox;
        py  = fminf(fmaxf(py,  -4.f), 100.f);
        pxx = fminf(fmaxf(pxx, -4.f), 100.f);
        float y0f = floorf(py), x0f = floorf(pxx);
        int y0 = (int)y0f, x0 = (int)x0f;
        cpos[i] = ((u32)(y0 + 4) << 16) | (u32)(x0 + 4);
        cwy[i] = py - y0f; cwx[i] = pxx - x0f;
    }

    f32x4 acc[4][4];
    #pragma unroll
    for (int mt = 0; mt < 4; ++mt)
        #pragma unroll
        for (int nf = 0; nf < 4; ++nf)
            acc[mt][nf] = (f32x4){0.f,0.f,0.f,0.f};

    int bbase[4];
    #pragma unroll
    for (int nf = 0; nf < 4; ++nf)
        bbase[nf] = (pg*64 + nf*16 + (lane & 15))*40 + colq*8;

    __syncthreads();

    for (int kc = 0; kc < NKC; ++kc) {
        int tt = kc >> 3, cc = kc & 7;
        // produce 32ch x 128px bilinear samples into SB (2 ch per thread)
        for (int i = tid; i < 2048; i += 512) {
            int chp = i >> 7, px = i & 127;
            int r = (tt << 7) + px;
            u32 cp = cpos[r];
            int y0 = (int)(cp >> 16) - 4, x0 = (int)(cp & 0xFFFF) - 4;
            float wy = cwy[r], wx = cwx[r];
            bool y0i = (y0 >= 0) & (y0 < HH);
            bool y1i = (y0 >= -1) & (y0 < HH-1);
            bool x0i = (x0 >= 0) & (x0 < WW);
            bool x1i = (x0 >= -1) & (x0 < WW-1);
            int a00 = y0*WW + x0;
            float omy = 1.f - wy, omx = 1.f - wx;
            const u16* p0 = src + (size_t)(cc*32 + chp*2)*HWSZ;
            u32 outpk = 0;
            #pragma unroll
            for (int j = 0; j < 2; ++j) {
                const u16* p = p0 + (size_t)j*HWSZ;
                float v00 = (y0i && x0i) ? bf2f(p[a00])          : 0.f;
                float v01 = (y0i && x1i) ? bf2f(p[a00 + 1])      : 0.f;
                float v10 = (y1i && x0i) ? bf2f(p[a00 + WW])     : 0.f;
                float v11 = (y1i && x1i) ? bf2f(p[a00 + WW + 1]) : 0.f;
                float sv = (v00*omy + v10*wy)*omx + (v01*omy + v11*wy)*wx;
                outpk |= (u32)f2bf(sv) << (16*j);
            }
            *reinterpret_cast<u32*>(&SB[px*40 + chp*2]) = outpk;
        }
        __syncthreads();
        bf16x8 a[4];
        #pragma unroll
        for (int mt = 0; mt < 4; ++mt)
            a[mt] = *reinterpret_cast<const bf16x8*>(
                Wp + (((size_t)(mh*4+mt)*NKC + kc)*64 + lane)*8);
        #pragma unroll
        for (int nf = 0; nf < 4; ++nf) {
            bf16x8 b = *reinterpret_cast<const bf16x8*>(&SB[bbase[nf]]);
            #pragma unroll
            for (int mt = 0; mt < 4; ++mt)
                acc[mt][nf] = __builtin_amdgcn_mfma_f32_16x16x32_bf16(
                                  a[mt], b, acc[mt][nf], 0, 0, 0);
        }
        __syncthreads();
    }

    #pragma unroll
    for (int nf = 0; nf < 4; ++nf) {
        int px = pg*64 + nf*16 + (lane & 15);
        int gp = (ty0 + (px>>5))*WW + tx0 + (px & 31);
        #pragma unroll
        for (int mt = 0; mt < 4; ++mt) {
            int o_base = (mh*4+mt)*16 + colq*4;
            #pragma unroll
            for (int r = 0; r < 4; ++r) {
                int o = o_base + r;
                alig[((size_t)n*CH + o)*HWSZ + gp] = f2bf(acc[mt][nf][r] + ab[o]);
            }
        }
    }
}

// ---------------------------------------------------------------------------
// final fusion: softmax over N of g, weighted sum of aligned(bf16), +emb, residual
__global__ void k_fuse(const float* __restrict__ cur,
                       const u16* __restrict__ alig,
                       const float* __restrict__ g,
                       const float* __restrict__ emb,
                       float* __restrict__ out)
{
    int idx = blockIdx.x * 256 + threadIdx.x;
    if (idx >= CH * HWSZ) return;
    int c = idx / HWSZ, p = idx % HWSZ;
    float e[NN]; float m = -1e30f;
    #pragma unroll
    for (int n = 0; n < NN; ++n) { e[n] = g[n*HWSZ + p]; m = fmaxf(m, e[n]); }
    float se = 0.f;
    #pragma unroll
    for (int n = 0; n < NN; ++n) { e[n] = expf(e[n] - m); se += e[n]; }
    float inv = 1.f / se;
    float s = 0.f;
    #pragma unroll
    for (int n = 0; n < NN; ++n)
        s += bf2f(alig[((size_t)n*CH + c)*HWSZ + p]) * e[n];
    s = s * inv + emb[c];
    out[idx] = cur[idx] + 0.5f * s;
}

// ---------------------------------------------------------------------------
extern "C" void kernel_launch(void* const* d_in, const int* in_sizes, int n_in,
                              void* d_out, int out_size, void* d_ws, size_t ws_size,
                              hipStream_t stream)
{
    const float* cur = (const float*)d_in[0];
    const float* nbr = (const float*)d_in[1];
    const float* cd  = (const float*)d_in[2];
    const float* aw  = (const float*)d_in[3];
    const float* ab  = (const float*)d_in[4];
    const float* ow  = (const float*)d_in[5];
    const float* ob  = (const float*)d_in[6];
    const float* g1w = (const float*)d_in[7];
    const float* g1b = (const float*)d_in[8];
    const float* g2w = (const float*)d_in[9];
    const float* g2b = (const float*)d_in[10];
    const float* ew  = (const float*)d_in[11];
    const float* eb  = (const float*)d_in[12];
    float* out = (float*)d_out;
    float* ws  = (float*)d_ws;

    float* offs = ws;                         // 1,327,104 f
    float* gbuf = offs + 1327104;             // 73,728 f
    float* emb  = gbuf + 73728;               // 256 f
    u16* nbrb = (u16*)(emb + 256);            // 18,874,368 u16
    u16* alig = nbrb + 18874368;              // 18,874,368 u16
    u16* wpO  = alig + 18874368;              // 32*4608  = 147,456 u16
    u16* wpG  = wpO + 147456;                 // 128*4608 = 589,824 u16
    u16* wpA  = wpG + 589824;                 // 256*2304 = 589,824 u16

    k_emb_sum<<<dim3(1), dim3(256), 0, stream>>>(cd, ew, eb, emb);
    k_tobf16<<<dim3(18432), dim3(256), 0, stream>>>(nbr, nbrb, 4718592);
    k_pack_w<<<dim3((32*4608 + 255)/256), dim3(256), 0, stream>>>(ow, wpO, 18, 32, 512);
    k_pack_w<<<dim3((128*4608 + 255)/256), dim3(256), 0, stream>>>(g1w, wpG, 128, 128, 512);
    k_pack_w<<<dim3((256*2304 + 255)/256), dim3(256), 0, stream>>>(aw, wpA, 256, 256, 256);

    // offset conv: concat(nbr_n, cur) -> 18 ch (padded to 32)
    k_conv_shift<1, 0, false, true><<<dim3(36, 8), dim3(512), 0, stream>>>(
        nbrb, (long)CH*HWSZ, cur, 0L, wpO, ob, nullptr, nullptr, offs);
    // deformable conv -> alig (bf16)
    k_deform_shift<<<dim3(72, 8), dim3(512), 0, stream>>>(nbrb, offs, wpA, ab, alig);
    // gate: concat(cur, alig_n) -> 128 -> relu -> 1x1 -> sigmoid
    k_conv_shift<4, 1, true, false><<<dim3(36, 8), dim3(512), 0, stream>>>(
        cur, 0L, alig, (long)CH*HWSZ, wpG, g1b, g2w, g2b, gbuf);
    // softmax + fuse + residual
    k_fuse<<<dim3((CH*HWSZ + 255)/256), dim3(256), 0, stream>>>(cur, alig, gbuf, emb, out);
}

// Round 4
// 491.046 us; speedup vs baseline: 8.1533x; 3.0482x over previous
//
#include <hip/hip_runtime.h>
#include <math.h>

// Problem constants: B=1, C=256, H=96, W=96, N=8
#define CH   256
#define HH   96
#define WW   96
#define NN   8
#define HWSZ 9216
#define PLANE (HWSZ*CH)          // elements per neighbor in NHWC

typedef unsigned short u16;
typedef unsigned int   u32;
typedef short bf16x8 __attribute__((ext_vector_type(8)));
typedef float f32x4  __attribute__((ext_vector_type(4)));

__device__ inline u16 f2bf(float f) {
    union { float f; u32 u; } v; v.f = f;
    u32 r = v.u + 0x7FFF + ((v.u >> 16) & 1);   // RNE
    return (u16)(r >> 16);
}
__device__ inline float bf2f(u16 h) {
    union { u32 u; float f; } v; v.u = (u32)h << 16; return v.f;
}
__device__ inline float bflo(u32 u) {
    union { u32 u; float f; } v; v.u = u << 16; return v.f;
}
__device__ inline float bfhi(u32 u) {
    union { u32 u; float f; } v; v.u = u & 0xffff0000u; return v.f;
}
__device__ inline u32 pk2bf(float lo, float hi) {   // RNE pack pair
    union { float f; u32 u; } a, b; a.f = lo; b.f = hi;
    u32 ra = a.u + 0x7FFF + ((a.u >> 16) & 1);
    u32 rb = b.u + 0x7FFF + ((b.u >> 16) & 1);
    return (ra >> 16) | (rb & 0xffff0000u);
}

// ---------------------------------------------------------------------------
__global__ void k_emb_sum(const float* __restrict__ cd,
                          const float* __restrict__ enc_w,
                          const float* __restrict__ enc_b,
                          float* __restrict__ emb)
{
    int c = threadIdx.x;
    float s = 0.f;
    for (int n = 0; n < NN; ++n) {
        float d = enc_b[c];
        #pragma unroll
        for (int j = 0; j < 4; ++j) d += cd[n*4 + j] * enc_w[c*4 + j];
        s += d;
    }
    emb[c] = s;
}

// ---------------------------------------------------------------------------
// NCHW f32 -> NHWC bf16. grid (48, N), block 256 (thread = channel).
// reads: per-thread sequential (L1-amortized); writes: 128B/wave coalesced.
__global__ void k_to_nhwc(const float* __restrict__ in, u16* __restrict__ out)
{
    int n = blockIdx.y, c = threadIdx.x;
    int p0 = blockIdx.x * 192;
    const float* src = in + ((size_t)n * CH + c) * HWSZ + p0;
    u16* dst = out + (size_t)n * PLANE + (size_t)p0 * CH + c;
    for (int j = 0; j < 192; ++j)
        dst[(size_t)j * CH] = f2bf(src[j]);
}

// ---------------------------------------------------------------------------
// pack conv weights w[O][CIN][3][3] (fp32 OIHW) -> bf16 A-fragment layout.
// K = tap*CIN + c; Wp[o>>4][K>>5][lane][8], lane=((K&31)>>3)*16+(o&15), j=K&7.
__global__ void k_pack_w(const float* __restrict__ w, u16* __restrict__ wp,
                         int O, int O_pad, int CIN)
{
    int idx = blockIdx.x * 256 + threadIdx.x;
    int total = O_pad * CIN * 9;
    if (idx >= total) return;
    int o = idx / (CIN * 9);
    int K = idx % (CIN * 9);
    int tap = K / CIN, c = K % CIN;
    float v = (o < O) ? w[((size_t)o * CIN + c) * 9 + tap] : 0.f;
    int NKC = (CIN * 9) >> 5;
    int kc = K >> 5, kl = K & 31;
    int lane = (kl >> 3) * 16 + (o & 15);
    size_t dstp = (((size_t)(o >> 4) * NKC + kc) * 64 + lane) * 8 + (kl & 7);
    wp[dstp] = f2bf(v);
}

// ---------------------------------------------------------------------------
// shift-conv 3x3 pad1 on concat(in0_n, in1_n) (512 in-ch, NHWC bf16) via MFMA.
// tile 8 rows x 32 cols (256 px), grid (36,8), block 512 = 8 waves.
// EPI 0: store fp32 planes (o<18) -> offs. EPI 1: gate epilogue -> gbuf.
template<int MTW, int EPI>
__global__ __launch_bounds__(512) void k_conv_nhwc(
    const u16* __restrict__ in0, long s0,
    const u16* __restrict__ in1, long s1,
    const u16* __restrict__ Wp, const float* __restrict__ b1,
    const float* __restrict__ g2w, const float* __restrict__ g2b,
    float* __restrict__ out)
{
    constexpr int NKC = 144, NCC = 16;
    int n = blockIdx.y, t = blockIdx.x;
    int tx0 = (t % 3) * 32, ty0 = (t / 3) * 8;
    int tid = threadIdx.x, lane = tid & 63, w = tid >> 6;
    int mh = w >> 2, pg = w & 3;
    int colq = lane >> 4;

    __shared__ __align__(16) u16 SB[340*40];
    __shared__ float gpart[8][64];

    f32x4 acc[MTW][4];
    #pragma unroll
    for (int mt = 0; mt < MTW; ++mt)
        #pragma unroll
        for (int nf = 0; nf < 4; ++nf)
            acc[mt][nf] = (f32x4){0.f,0.f,0.f,0.f};

    int bidx[4];
    #pragma unroll
    for (int nf = 0; nf < 4; ++nf) {
        int px = pg*64 + nf*16 + (lane & 15);
        int row = px >> 5, col = px & 31;
        bidx[nf] = ((row+1)*34 + (col+1))*40 + colq*8;
    }

    for (int cc = 0; cc < NCC; ++cc) {
        const u16* base = (cc < 8) ? in0 + (size_t)n*s0 + cc*32
                                   : in1 + (size_t)n*s1 + (cc-8)*32;
        for (int i = tid; i < 1360; i += 512) {
            int ph = i >> 2, q = i & 3;
            int r = ph / 34, col = ph - r*34;
            int y = ty0 - 1 + r, x = tx0 - 1 + col;
            bool v = ((unsigned)y < (unsigned)HH) && ((unsigned)x < (unsigned)WW);
            int off = v ? (y*WW + x)*CH : 0;
            int4 val = *reinterpret_cast<const int4*>(base + off + q*8);
            if (!v) val = make_int4(0,0,0,0);
            *reinterpret_cast<int4*>(&SB[ph*40 + q*8]) = val;
        }
        __syncthreads();
        #pragma unroll
        for (int tap = 0; tap < 9; ++tap) {
            int kc = tap*NCC + cc;
            bf16x8 a[MTW];
            #pragma unroll
            for (int mt = 0; mt < MTW; ++mt)
                a[mt] = *reinterpret_cast<const bf16x8*>(
                    Wp + (((size_t)(mh*MTW+mt)*NKC + kc)*64 + lane)*8);
            const int dy = tap/3 - 1, dx = tap%3 - 1;
            #pragma unroll
            for (int nf = 0; nf < 4; ++nf) {
                bf16x8 b = *reinterpret_cast<const bf16x8*>(
                    &SB[bidx[nf] + (dy*34 + dx)*40]);
                #pragma unroll
                for (int mt = 0; mt < MTW; ++mt)
                    acc[mt][nf] = __builtin_amdgcn_mfma_f32_16x16x32_bf16(
                                      a[mt], b, acc[mt][nf], 0, 0, 0);
            }
        }
        __syncthreads();
    }

    if (EPI == 0) {
        #pragma unroll
        for (int nf = 0; nf < 4; ++nf) {
            int px = pg*64 + nf*16 + (lane & 15);
            int gp = (ty0 + (px>>5))*WW + tx0 + (px & 31);
            #pragma unroll
            for (int mt = 0; mt < MTW; ++mt) {
                int o_base = (mh*MTW+mt)*16 + colq*4;
                #pragma unroll
                for (int r = 0; r < 4; ++r) {
                    int o = o_base + r;
                    if (o < 18)
                        out[((size_t)n*18 + o)*HWSZ + gp] = acc[mt][nf][r] + b1[o];
                }
            }
        }
    } else {
        float part[4];
        #pragma unroll
        for (int nf = 0; nf < 4; ++nf) {
            float s = 0.f;
            #pragma unroll
            for (int mt = 0; mt < MTW; ++mt) {
                int o_base = (mh*MTW+mt)*16 + colq*4;
                #pragma unroll
                for (int r = 0; r < 4; ++r) {
                    int o = o_base + r;
                    float vv = fmaxf(acc[mt][nf][r] + b1[o], 0.f);
                    s += vv * g2w[o];
                }
            }
            part[nf] = s;
        }
        #pragma unroll
        for (int nf = 0; nf < 4; ++nf) {
            part[nf] += __shfl_xor(part[nf], 16, 64);
            part[nf] += __shfl_xor(part[nf], 32, 64);
        }
        if (lane < 16) {
            #pragma unroll
            for (int nf = 0; nf < 4; ++nf)
                gpart[w][nf*16 + lane] = part[nf];
        }
        __syncthreads();
        if (tid < 256) {
            int pxl = tid & 63, pgg = tid >> 6;
            float s = gpart[pgg][pxl] + gpart[4 + pgg][pxl] + g2b[0];
            float g = 1.f / (1.f + expf(-s));
            int px = pgg*64 + pxl;
            int gp = (ty0 + (px>>5))*WW + tx0 + (px & 31);
            out[(size_t)n*HWSZ + gp] = g;
        }
    }
}

// ---------------------------------------------------------------------------
// deformable 3x3 conv via bf16 MFMA, NHWC in/out.
// tile 4 rows x 32 cols (128 px), grid (72,8), block 512 = 8 waves.
// wave w: mh = w>>1 (64 oc), pg = w&1 (64-px group).
__global__ __launch_bounds__(512) void k_deform_nhwc(
    const u16* __restrict__ nbrh, const float* __restrict__ offs,
    const u16* __restrict__ Wp, const float* __restrict__ ab,
    u16* __restrict__ alig)
{
    constexpr int NKC = 72;
    int n = blockIdx.y, t = blockIdx.x;
    int tx0 = (t % 3) * 32, ty0 = (t / 3) * 4;
    int tid = threadIdx.x, lane = tid & 63, w = tid >> 6;
    int mh = w >> 1, pg = w & 1;
    int colq = lane >> 4;

    __shared__ __align__(16) u16 SBm[2][5120];   // dbuf [px128][40]
    __shared__ u32   cpos[1152];
    __shared__ float cwy[1152], cwx[1152];

    const u16* src = nbrh + (size_t)n * PLANE;

    // bilinear coords for 9 taps x 128 px
    for (int i = tid; i < 1152; i += 512) {
        int tt = i >> 7, px = i & 127;
        int y = ty0 + (px>>5), x = tx0 + (px & 31);
        int pp = y*WW + x;
        float oy = offs[((size_t)n*18 + 2*tt    )*HWSZ + pp];
        float ox = offs[((size_t)n*18 + 2*tt + 1)*HWSZ + pp];
        float py  = (float)y + (float)(tt/3 - 1) + oy;
        float pxx = (float)x + (float)(tt%3 - 1) + ox;
        py  = fminf(fmaxf(py,  -4.f), 100.f);
        pxx = fminf(fmaxf(pxx, -4.f), 100.f);
        float y0f = floorf(py), x0f = floorf(pxx);
        cpos[i] = ((u32)((int)y0f + 4) << 16) | (u32)((int)x0f + 4);
        cwy[i] = py - y0f; cwx[i] = pxx - x0f;
    }
    __syncthreads();

    f32x4 acc[4][4];
    #pragma unroll
    for (int mt = 0; mt < 4; ++mt)
        #pragma unroll
        for (int nf = 0; nf < 4; ++nf)
            acc[mt][nf] = (f32x4){0.f,0.f,0.f,0.f};

    int px = tid >> 2, chq = tid & 3;            // produce mapping
    int sbw = px*40 + chq*8;
    int bb[4];
    #pragma unroll
    for (int nf = 0; nf < 4; ++nf)
        bb[nf] = (pg*64 + nf*16 + (lane & 15))*40 + colq*8;

    auto loadC = [&](int kc, int4* q) {
        int tt = kc >> 3, cc = kc & 7;
        int r = (tt<<7) + px;
        u32 cp = cpos[r];
        int y0 = (int)(cp >> 16) - 4, x0 = (int)(cp & 0xffff) - 4;
        bool y0i = (y0 >= 0) & (y0 < HH);
        bool y1i = (y0 >= -1) & (y0 < HH-1);
        bool x0i = (x0 >= 0) & (x0 < WW);
        bool x1i = (x0 >= -1) & (x0 < WW-1);
        int c0 = cc*32 + chq*8;
        int a00 = (y0*WW + x0)*CH + c0;
        int o00 = (y0i & x0i) ? a00            : 0;
        int o01 = (y0i & x1i) ? a00 + CH       : 0;
        int o10 = (y1i & x0i) ? a00 + WW*CH    : 0;
        int o11 = (y1i & x1i) ? a00 + WW*CH+CH : 0;
        int4 z = make_int4(0,0,0,0);
        int4 q0 = *reinterpret_cast<const int4*>(src + o00);
        int4 q1 = *reinterpret_cast<const int4*>(src + o01);
        int4 q2 = *reinterpret_cast<const int4*>(src + o10);
        int4 q3 = *reinterpret_cast<const int4*>(src + o11);
        q[0] = (y0i & x0i) ? q0 : z;
        q[1] = (y0i & x1i) ? q1 : z;
        q[2] = (y1i & x0i) ? q2 : z;
        q[3] = (y1i & x1i) ? q3 : z;
    };
    auto bilerp = [&](int kc, const int4* q) -> int4 {
        int r = ((kc >> 3)<<7) + px;
        float wy = cwy[r], wx = cwx[r];
        float w00 = (1.f-wy)*(1.f-wx), w01 = (1.f-wy)*wx;
        float w10 = wy*(1.f-wx),       w11 = wy*wx;
        int4 res;
        #pragma unroll
        for (int j = 0; j < 4; ++j) {
            u32 u00 = ((const u32*)&q[0])[j], u01 = ((const u32*)&q[1])[j];
            u32 u10 = ((const u32*)&q[2])[j], u11 = ((const u32*)&q[3])[j];
            float lo = w00*bflo(u00) + w01*bflo(u01) + w10*bflo(u10) + w11*bflo(u11);
            float hi = w00*bfhi(u00) + w01*bfhi(u01) + w10*bfhi(u10) + w11*bfhi(u11);
            ((u32*)&res)[j] = pk2bf(lo, hi);
        }
        return res;
    };

    int4 crn[4];
    loadC(0, crn);
    int cur = 0;
    for (int kc = 0; kc < NKC; ++kc) {
        int4 vpk = bilerp(kc, crn);
        if (kc + 1 < NKC) loadC(kc + 1, crn);    // prefetch (T14)
        *reinterpret_cast<int4*>(&SBm[cur][sbw]) = vpk;
        __syncthreads();
        bf16x8 a4[4];
        #pragma unroll
        for (int mt = 0; mt < 4; ++mt)
            a4[mt] = *reinterpret_cast<const bf16x8*>(
                Wp + (((size_t)(mh*4+mt)*NKC + kc)*64 + lane)*8);
        #pragma unroll
        for (int nf = 0; nf < 4; ++nf) {
            bf16x8 b = *reinterpret_cast<const bf16x8*>(&SBm[cur][bb[nf]]);
            #pragma unroll
            for (int mt = 0; mt < 4; ++mt)
                acc[mt][nf] = __builtin_amdgcn_mfma_f32_16x16x32_bf16(
                                  a4[mt], b, acc[mt][nf], 0, 0, 0);
        }
        cur ^= 1;
    }

    // epilogue: LDS transpose -> coalesced NHWC writes. TO = [32 px][264]
    __syncthreads();
    u16* TO = &SBm[0][0];
    u16* aligp = alig + (size_t)n * PLANE;
    #pragma unroll
    for (int nf = 0; nf < 4; ++nf) {
        int pl = pg*16 + (lane & 15);
        #pragma unroll
        for (int mt = 0; mt < 4; ++mt) {
            int o = (mh*4+mt)*16 + colq*4;
            ushort4 v;
            v.x = f2bf(acc[mt][nf][0] + ab[o]);
            v.y = f2bf(acc[mt][nf][1] + ab[o+1]);
            v.z = f2bf(acc[mt][nf][2] + ab[o+2]);
            v.w = f2bf(acc[mt][nf][3] + ab[o+3]);
            *reinterpret_cast<ushort4*>(&TO[pl*264 + o]) = v;
        }
        __syncthreads();
        for (int i = tid; i < 1024; i += 512) {
            int pr = i >> 5, ck = i & 31;
            int pxx = (pr >> 4)*64 + nf*16 + (pr & 15);
            int gp = (ty0 + (pxx>>5))*WW + tx0 + (pxx & 31);
            *reinterpret_cast<int4*>(aligp + (size_t)gp*CH + ck*8) =
                *reinterpret_cast<const int4*>(&TO[pr*264 + ck*8]);
        }
        __syncthreads();
    }
}

// ---------------------------------------------------------------------------
// fuse: softmax over N of g, weighted sum of alig (NHWC bf16), +emb, residual.
// block 256, 32 px per block, LDS-transposed for coalesced NCHW output.
__global__ __launch_bounds__(256) void k_fuse_nhwc(
    const float* __restrict__ cur, const u16* __restrict__ alig,
    const float* __restrict__ g, const float* __restrict__ emb,
    float* __restrict__ out)
{
    int p0 = blockIdx.x * 32;
    int tid = threadIdx.x;
    __shared__ float wE[NN][32];
    __shared__ float trans[256][33];

    if (tid < 32) {
        int p = p0 + tid;
        float e[NN], m = -1e30f;
        #pragma unroll
        for (int n = 0; n < NN; ++n) { e[n] = g[n*HWSZ + p]; m = fmaxf(m, e[n]); }
        float se = 0.f;
        #pragma unroll
        for (int n = 0; n < NN; ++n) { e[n] = expf(e[n] - m); se += e[n]; }
        float inv = 1.f / se;
        #pragma unroll
        for (int n = 0; n < NN; ++n) wE[n][tid] = e[n] * inv;
    }
    __syncthreads();

    #pragma unroll
    for (int it = 0; it < 4; ++it) {
        int i = tid + it*256;
        int px = i >> 5, ck = i & 31;
        float a8[8];
        #pragma unroll
        for (int j = 0; j < 8; ++j) a8[j] = 0.f;
        #pragma unroll
        for (int n = 0; n < NN; ++n) {
            int4 v = *reinterpret_cast<const int4*>(
                &alig[((size_t)n*HWSZ + p0 + px)*CH + ck*8]);
            float f = wE[n][px];
            #pragma unroll
            for (int j4 = 0; j4 < 4; ++j4) {
                u32 u = ((const u32*)&v)[j4];
                a8[2*j4]   += bflo(u) * f;
                a8[2*j4+1] += bfhi(u) * f;
            }
        }
        #pragma unroll
        for (int j = 0; j < 8; ++j) {
            int c = ck*8 + j;
            trans[c][px ^ (c & 31)] = a8[j] + emb[c];
        }
    }
    __syncthreads();
    for (int it = 0; it < 32; ++it) {
        int c = (tid >> 5) + it*8, px = tid & 31;
        int idx = c*HWSZ + p0 + px;
        out[idx] = cur[idx] + 0.5f * trans[c][px ^ (c & 31)];
    }
}

// ---------------------------------------------------------------------------
extern "C" void kernel_launch(void* const* d_in, const int* in_sizes, int n_in,
                              void* d_out, int out_size, void* d_ws, size_t ws_size,
                              hipStream_t stream)
{
    const float* cur = (const float*)d_in[0];
    const float* nbr = (const float*)d_in[1];
    const float* cd  = (const float*)d_in[2];
    const float* aw  = (const float*)d_in[3];
    const float* ab  = (const float*)d_in[4];
    const float* ow  = (const float*)d_in[5];
    const float* ob  = (const float*)d_in[6];
    const float* g1w = (const float*)d_in[7];
    const float* g1b = (const float*)d_in[8];
    const float* g2w = (const float*)d_in[9];
    const float* g2b = (const float*)d_in[10];
    const float* ew  = (const float*)d_in[11];
    const float* eb  = (const float*)d_in[12];
    float* out = (float*)d_out;
    float* ws  = (float*)d_ws;

    float* offs = ws;                          // 1,327,104 f
    float* gbuf = offs + 1327104;              // 73,728 f
    float* emb  = gbuf + 73728;                // 256 f
    u16* nbrh = (u16*)(emb + 256);             // 8 * PLANE
    u16* curh = nbrh + (size_t)NN*PLANE;       // PLANE
    u16* alig = curh + PLANE;                  // 8 * PLANE (NHWC)
    u16* wpO  = alig + (size_t)NN*PLANE;       // 32*4608
    u16* wpG  = wpO + 147456;                  // 128*4608
    u16* wpA  = wpG + 589824;                  // 256*2304

    k_emb_sum<<<dim3(1), dim3(256), 0, stream>>>(cd, ew, eb, emb);
    k_to_nhwc<<<dim3(48, 8), dim3(256), 0, stream>>>(nbr, nbrh);
    k_to_nhwc<<<dim3(48, 1), dim3(256), 0, stream>>>(cur, curh);
    k_pack_w<<<dim3((32*4608 + 255)/256), dim3(256), 0, stream>>>(ow, wpO, 18, 32, 512);
    k_pack_w<<<dim3((128*4608 + 255)/256), dim3(256), 0, stream>>>(g1w, wpG, 128, 128, 512);
    k_pack_w<<<dim3((256*2304 + 255)/256), dim3(256), 0, stream>>>(aw, wpA, 256, 256, 256);

    // offset conv: concat(nbr_n, cur) -> 18 ch (padded to 32)
    k_conv_nhwc<1, 0><<<dim3(36, 8), dim3(512), 0, stream>>>(
        nbrh, (long)PLANE, curh, 0L, wpO, ob, nullptr, nullptr, offs);
    // deformable conv -> alig (NHWC bf16)
    k_deform_nhwc<<<dim3(72, 8), dim3(512), 0, stream>>>(nbrh, offs, wpA, ab, alig);
    // gate: concat(cur, alig_n) -> 128 -> relu -> 1x1 -> sigmoid
    k_conv_nhwc<4, 1><<<dim3(36, 8), dim3(512), 0, stream>>>(
        curh, 0L, alig, (long)PLANE, wpG, g1b, g2w, g2b, gbuf);
    // softmax + fuse + residual
    k_fuse_nhwc<<<dim3(288), dim3(256), 0, stream>>>(cur, alig, gbuf, emb, out);
}

// Round 5
// 434.055 us; speedup vs baseline: 9.2239x; 1.1313x over previous
//
#include <hip/hip_runtime.h>
#include <math.h>

// Problem constants: B=1, C=256, H=96, W=96, N=8
#define CH   256
#define HH   96
#define WW   96
#define NN   8
#define HWSZ 9216
#define PLANE (HWSZ*CH)          // elements per neighbor in NHWC

typedef unsigned short u16;
typedef unsigned int   u32;
typedef short bf16x8 __attribute__((ext_vector_type(8)));
typedef float f32x4  __attribute__((ext_vector_type(4)));

__device__ inline u16 f2bf(float f) {
    union { float f; u32 u; } v; v.f = f;
    u32 r = v.u + 0x7FFF + ((v.u >> 16) & 1);   // RNE
    return (u16)(r >> 16);
}
__device__ inline float bflo(u32 u) {
    union { u32 u; float f; } v; v.u = u << 16; return v.f;
}
__device__ inline float bfhi(u32 u) {
    union { u32 u; float f; } v; v.u = u & 0xffff0000u; return v.f;
}
__device__ inline u32 pk2bf(float lo, float hi) {   // RNE pack pair
    union { float f; u32 u; } a, b; a.f = lo; b.f = hi;
    u32 ra = a.u + 0x7FFF + ((a.u >> 16) & 1);
    u32 rb = b.u + 0x7FFF + ((b.u >> 16) & 1);
    return (ra >> 16) | (rb & 0xffff0000u);
}

// ---------------------------------------------------------------------------
__global__ void k_emb_sum(const float* __restrict__ cd,
                          const float* __restrict__ enc_w,
                          const float* __restrict__ enc_b,
                          float* __restrict__ emb)
{
    int c = threadIdx.x;
    float s = 0.f;
    for (int n = 0; n < NN; ++n) {
        float d = enc_b[c];
        #pragma unroll
        for (int j = 0; j < 4; ++j) d += cd[n*4 + j] * enc_w[c*4 + j];
        s += d;
    }
    emb[c] = s;
}

// ---------------------------------------------------------------------------
// NCHW f32 -> NHWC bf16. grid (48, N), block 256 (thread = channel).
__global__ void k_to_nhwc(const float* __restrict__ in, u16* __restrict__ out)
{
    int n = blockIdx.y, c = threadIdx.x;
    int p0 = blockIdx.x * 192;
    const float* src = in + ((size_t)n * CH + c) * HWSZ + p0;
    u16* dst = out + (size_t)n * PLANE + (size_t)p0 * CH + c;
    for (int j = 0; j < 192; ++j)
        dst[(size_t)j * CH] = f2bf(src[j]);
}

// ---------------------------------------------------------------------------
// pack conv weights w[O][CIN][3][3] (fp32 OIHW) -> bf16 A-fragment layout.
// K = tap*CIN + c; Wp[o>>4][K>>5][lane][8], lane=((K&31)>>3)*16+(o&15), j=K&7.
__global__ void k_pack_w(const float* __restrict__ w, u16* __restrict__ wp,
                         int O, int O_pad, int CIN)
{
    int idx = blockIdx.x * 256 + threadIdx.x;
    int total = O_pad * CIN * 9;
    if (idx >= total) return;
    int o = idx / (CIN * 9);
    int K = idx % (CIN * 9);
    int tap = K / CIN, c = K % CIN;
    float v = (o < O) ? w[((size_t)o * CIN + c) * 9 + tap] : 0.f;
    int NKC = (CIN * 9) >> 5;
    int kc = K >> 5, kl = K & 31;
    int lane = (kl >> 3) * 16 + (o & 15);
    size_t dstp = (((size_t)(o >> 4) * NKC + kc) * 64 + lane) * 8 + (kl & 7);
    wp[dstp] = f2bf(v);
}

// ---------------------------------------------------------------------------
// shift-conv 3x3 pad1 on concat(in0_n, in1_n) (512 in-ch, NHWC bf16) via MFMA.
// tile 8 rows x 32 cols (256 px), grid (8, 36) [XCD-pinned n], block 512.
// EPI 0: store fp32 planes (o<18) -> offs. EPI 1: gate epilogue -> gbuf.
template<int MTW, int EPI>
__global__ __launch_bounds__(512) void k_conv_nhwc(
    const u16* __restrict__ in0, long s0,
    const u16* __restrict__ in1, long s1,
    const u16* __restrict__ Wp, const float* __restrict__ b1,
    const float* __restrict__ g2w, const float* __restrict__ g2b,
    float* __restrict__ out)
{
    constexpr int NKC = 144, NCC = 16;
    int n = blockIdx.x, t = blockIdx.y;
    int tx0 = (t % 3) * 32, ty0 = (t / 3) * 8;
    int tid = threadIdx.x, lane = tid & 63, w = tid >> 6;
    int mh = w >> 2, pg = w & 3;
    int colq = lane >> 4;

    __shared__ __align__(16) u16 SB[340*40];
    __shared__ float gpart[8][64];

    f32x4 acc[MTW][4];
    #pragma unroll
    for (int mt = 0; mt < MTW; ++mt)
        #pragma unroll
        for (int nf = 0; nf < 4; ++nf)
            acc[mt][nf] = (f32x4){0.f,0.f,0.f,0.f};

    int bidx[4];
    #pragma unroll
    for (int nf = 0; nf < 4; ++nf) {
        int px = pg*64 + nf*16 + (lane & 15);
        int row = px >> 5, col = px & 31;
        bidx[nf] = ((row+1)*34 + (col+1))*40 + colq*8;
    }

    for (int cc = 0; cc < NCC; ++cc) {
        const u16* base = (cc < 8) ? in0 + (size_t)n*s0 + cc*32
                                   : in1 + (size_t)n*s1 + (cc-8)*32;
        for (int i = tid; i < 1360; i += 512) {
            int ph = i >> 2, q = i & 3;
            int r = ph / 34, col = ph - r*34;
            int y = ty0 - 1 + r, x = tx0 - 1 + col;
            bool v = ((unsigned)y < (unsigned)HH) && ((unsigned)x < (unsigned)WW);
            int off = v ? (y*WW + x)*CH : 0;
            int4 val = *reinterpret_cast<const int4*>(base + off + q*8);
            if (!v) val = make_int4(0,0,0,0);
            *reinterpret_cast<int4*>(&SB[ph*40 + q*8]) = val;
        }
        __syncthreads();
        #pragma unroll
        for (int tap = 0; tap < 9; ++tap) {
            int kc = tap*NCC + cc;
            bf16x8 a[MTW];
            #pragma unroll
            for (int mt = 0; mt < MTW; ++mt)
                a[mt] = *reinterpret_cast<const bf16x8*>(
                    Wp + (((size_t)(mh*MTW+mt)*NKC + kc)*64 + lane)*8);
            const int dy = tap/3 - 1, dx = tap%3 - 1;
            #pragma unroll
            for (int nf = 0; nf < 4; ++nf) {
                bf16x8 b = *reinterpret_cast<const bf16x8*>(
                    &SB[bidx[nf] + (dy*34 + dx)*40]);
                #pragma unroll
                for (int mt = 0; mt < MTW; ++mt)
                    acc[mt][nf] = __builtin_amdgcn_mfma_f32_16x16x32_bf16(
                                      a[mt], b, acc[mt][nf], 0, 0, 0);
            }
        }
        __syncthreads();
    }

    if (EPI == 0) {
        #pragma unroll
        for (int nf = 0; nf < 4; ++nf) {
            int px = pg*64 + nf*16 + (lane & 15);
            int gp = (ty0 + (px>>5))*WW + tx0 + (px & 31);
            #pragma unroll
            for (int mt = 0; mt < MTW; ++mt) {
                int o_base = (mh*MTW+mt)*16 + colq*4;
                #pragma unroll
                for (int r = 0; r < 4; ++r) {
                    int o = o_base + r;
                    if (o < 18)
                        out[((size_t)n*18 + o)*HWSZ + gp] = acc[mt][nf][r] + b1[o];
                }
            }
        }
    } else {
        float part[4];
        #pragma unroll
        for (int nf = 0; nf < 4; ++nf) {
            float s = 0.f;
            #pragma unroll
            for (int mt = 0; mt < MTW; ++mt) {
                int o_base = (mh*MTW+mt)*16 + colq*4;
                #pragma unroll
                for (int r = 0; r < 4; ++r) {
                    int o = o_base + r;
                    float vv = fmaxf(acc[mt][nf][r] + b1[o], 0.f);
                    s += vv * g2w[o];
                }
            }
            part[nf] = s;
        }
        #pragma unroll
        for (int nf = 0; nf < 4; ++nf) {
            part[nf] += __shfl_xor(part[nf], 16, 64);
            part[nf] += __shfl_xor(part[nf], 32, 64);
        }
        if (lane < 16) {
            #pragma unroll
            for (int nf = 0; nf < 4; ++nf)
                gpart[w][nf*16 + lane] = part[nf];
        }
        __syncthreads();
        if (tid < 256) {
            int pxl = tid & 63, pgg = tid >> 6;
            float s = gpart[pgg][pxl] + gpart[4 + pgg][pxl] + g2b[0];
            float g = 1.f / (1.f + expf(-s));
            int px = pgg*64 + pxl;
            int gp = (ty0 + (px>>5))*WW + tx0 + (px & 31);
            out[(size_t)n*HWSZ + gp] = g;
        }
    }
}

// ---------------------------------------------------------------------------
// deformable 3x3 conv via bf16 MFMA, NHWC in/out.
// tile 2 rows x 32 cols (64 px), grid (8, 144) [XCD-pinned n], block 256 = 4
// waves; wave w owns oc [w*64, w*64+64).
__global__ __launch_bounds__(256) void k_deform_nhwc(
    const u16* __restrict__ nbrh, const float* __restrict__ offs,
    const u16* __restrict__ Wp, const float* __restrict__ ab,
    u16* __restrict__ alig)
{
    constexpr int NKC = 72;
    int n = blockIdx.x, t = blockIdx.y;
    int tx0 = (t % 3) * 32, ty0 = (t / 3) * 2;
    int tid = threadIdx.x, lane = tid & 63, w = tid >> 6;
    int colq = lane >> 4;

    __shared__ __align__(16) u16 pool[8448];      // SBm[2][2560] | TO[32][264]
    __shared__ u32   cpos[576];
    __shared__ float cwy[576], cwx[576];
    u16* SB0 = pool;
    u16* SB1 = pool + 2560;

    const u16* src = nbrh + (size_t)n * PLANE;

    // bilinear coords for 9 taps x 64 px
    for (int i = tid; i < 576; i += 256) {
        int tt = i >> 6, px = i & 63;
        int y = ty0 + (px>>5), x = tx0 + (px & 31);
        int pp = y*WW + x;
        float oy = offs[((size_t)n*18 + 2*tt    )*HWSZ + pp];
        float ox = offs[((size_t)n*18 + 2*tt + 1)*HWSZ + pp];
        float py  = (float)y + (float)(tt/3 - 1) + oy;
        float pxx = (float)x + (float)(tt%3 - 1) + ox;
        py  = fminf(fmaxf(py,  -4.f), 100.f);
        pxx = fminf(fmaxf(pxx, -4.f), 100.f);
        float y0f = floorf(py), x0f = floorf(pxx);
        cpos[i] = ((u32)((int)y0f + 4) << 16) | (u32)((int)x0f + 4);
        cwy[i] = py - y0f; cwx[i] = pxx - x0f;
    }
    __syncthreads();

    f32x4 acc[4][4];
    #pragma unroll
    for (int mt = 0; mt < 4; ++mt)
        #pragma unroll
        for (int nf = 0; nf < 4; ++nf)
            acc[mt][nf] = (f32x4){0.f,0.f,0.f,0.f};

    int px = tid >> 2, chq = tid & 3;            // produce mapping (64px x 4 q)
    int sbw = px*40 + chq*8;
    int bb[4];
    #pragma unroll
    for (int nf = 0; nf < 4; ++nf)
        bb[nf] = (nf*16 + (lane & 15))*40 + colq*8;

    auto loadC = [&](int kc, int4* q) {
        int tt = kc >> 3, cc = kc & 7;
        int r = (tt<<6) + px;
        u32 cp = cpos[r];
        int y0 = (int)(cp >> 16) - 4, x0 = (int)(cp & 0xffff) - 4;
        bool y0i = (y0 >= 0) & (y0 < HH);
        bool y1i = (y0 >= -1) & (y0 < HH-1);
        bool x0i = (x0 >= 0) & (x0 < WW);
        bool x1i = (x0 >= -1) & (x0 < WW-1);
        int c0 = cc*32 + chq*8;
        int a00 = (y0*WW + x0)*CH + c0;
        int o00 = (y0i & x0i) ? a00            : 0;
        int o01 = (y0i & x1i) ? a00 + CH       : 0;
        int o10 = (y1i & x0i) ? a00 + WW*CH    : 0;
        int o11 = (y1i & x1i) ? a00 + WW*CH+CH : 0;
        int4 z = make_int4(0,0,0,0);
        int4 q0 = *reinterpret_cast<const int4*>(src + o00);
        int4 q1 = *reinterpret_cast<const int4*>(src + o01);
        int4 q2 = *reinterpret_cast<const int4*>(src + o10);
        int4 q3 = *reinterpret_cast<const int4*>(src + o11);
        q[0] = (y0i & x0i) ? q0 : z;
        q[1] = (y0i & x1i) ? q1 : z;
        q[2] = (y1i & x0i) ? q2 : z;
        q[3] = (y1i & x1i) ? q3 : z;
    };
    auto bilerp = [&](int kc, const int4* q) -> int4 {
        int r = ((kc >> 3)<<6) + px;
        float wy = cwy[r], wx = cwx[r];
        float w00 = (1.f-wy)*(1.f-wx), w01 = (1.f-wy)*wx;
        float w10 = wy*(1.f-wx),       w11 = wy*wx;
        int4 res;
        #pragma unroll
        for (int j = 0; j < 4; ++j) {
            u32 u00 = ((const u32*)&q[0])[j], u01 = ((const u32*)&q[1])[j];
            u32 u10 = ((const u32*)&q[2])[j], u11 = ((const u32*)&q[3])[j];
            float lo = w00*bflo(u00) + w01*bflo(u01) + w10*bflo(u10) + w11*bflo(u11);
            float hi = w00*bfhi(u00) + w01*bfhi(u01) + w10*bfhi(u10) + w11*bfhi(u11);
            ((u32*)&res)[j] = pk2bf(lo, hi);
        }
        return res;
    };
    auto loadA = [&](int kc, bf16x8* a) {
        #pragma unroll
        for (int mt = 0; mt < 4; ++mt)
            a[mt] = *reinterpret_cast<const bf16x8*>(
                Wp + (((size_t)(w*4+mt)*NKC + kc)*64 + lane)*8);
    };

    int4 crn[4];
    bf16x8 apf[4];
    loadC(0, crn);
    loadA(0, apf);
    int cur = 0;
    for (int kc = 0; kc < NKC; ++kc) {
        int4 vpk = bilerp(kc, crn);
        u16* SBc = cur ? SB1 : SB0;
        *reinterpret_cast<int4*>(&SBc[sbw]) = vpk;
        bf16x8 a4[4];
        #pragma unroll
        for (int mt = 0; mt < 4; ++mt) a4[mt] = apf[mt];
        if (kc + 1 < NKC) { loadC(kc + 1, crn); loadA(kc + 1, apf); }  // T14
        __syncthreads();
        #pragma unroll
        for (int nf = 0; nf < 4; ++nf) {
            bf16x8 b = *reinterpret_cast<const bf16x8*>(&SBc[bb[nf]]);
            #pragma unroll
            for (int mt = 0; mt < 4; ++mt)
                acc[mt][nf] = __builtin_amdgcn_mfma_f32_16x16x32_bf16(
                                  a4[mt], b, acc[mt][nf], 0, 0, 0);
        }
        cur ^= 1;
    }

    // epilogue: LDS transpose -> coalesced NHWC writes. TO = [32 px][264]
    __syncthreads();
    u16* TO = pool;
    u16* aligp = alig + (size_t)n * PLANE;
    #pragma unroll
    for (int h = 0; h < 2; ++h) {
        #pragma unroll
        for (int sub = 0; sub < 2; ++sub) {
            int nf = 2*h + sub;
            int pl = sub*16 + (lane & 15);
            #pragma unroll
            for (int mt = 0; mt < 4; ++mt) {
                int o = (w*4+mt)*16 + colq*4;
                ushort4 v;
                v.x = f2bf(acc[mt][nf][0] + ab[o]);
                v.y = f2bf(acc[mt][nf][1] + ab[o+1]);
                v.z = f2bf(acc[mt][nf][2] + ab[o+2]);
                v.w = f2bf(acc[mt][nf][3] + ab[o+3]);
                *reinterpret_cast<ushort4*>(&TO[pl*264 + o]) = v;
            }
        }
        __syncthreads();
        #pragma unroll
        for (int it = 0; it < 4; ++it) {
            int i = tid + it*256;
            int pr = i >> 5, ck = i & 31;
            int nf = 2*h + (pr >> 4);
            int pxx = nf*16 + (pr & 15);
            int gp = (ty0 + (pxx>>5))*WW + tx0 + (pxx & 31);
            *reinterpret_cast<int4*>(aligp + (size_t)gp*CH + ck*8) =
                *reinterpret_cast<const int4*>(&TO[pr*264 + ck*8]);
        }
        __syncthreads();
    }
}

// ---------------------------------------------------------------------------
// fuse: softmax over N of g, weighted sum of alig (NHWC bf16), +emb, residual.
__global__ __launch_bounds__(256) void k_fuse_nhwc(
    const float* __restrict__ cur, const u16* __restrict__ alig,
    const float* __restrict__ g, const float* __restrict__ emb,
    float* __restrict__ out)
{
    int p0 = blockIdx.x * 32;
    int tid = threadIdx.x;
    __shared__ float wE[NN][32];
    __shared__ float trans[256][33];

    if (tid < 32) {
        int p = p0 + tid;
        float e[NN], m = -1e30f;
        #pragma unroll
        for (int n = 0; n < NN; ++n) { e[n] = g[n*HWSZ + p]; m = fmaxf(m, e[n]); }
        float se = 0.f;
        #pragma unroll
        for (int n = 0; n < NN; ++n) { e[n] = expf(e[n] - m); se += e[n]; }
        float inv = 1.f / se;
        #pragma unroll
        for (int n = 0; n < NN; ++n) wE[n][tid] = e[n] * inv;
    }
    __syncthreads();

    #pragma unroll
    for (int it = 0; it < 4; ++it) {
        int i = tid + it*256;
        int px = i >> 5, ck = i & 31;
        float a8[8];
        #pragma unroll
        for (int j = 0; j < 8; ++j) a8[j] = 0.f;
        #pragma unroll
        for (int n = 0; n < NN; ++n) {
            int4 v = *reinterpret_cast<const int4*>(
                &alig[((size_t)n*HWSZ + p0 + px)*CH + ck*8]);
            float f = wE[n][px];
            #pragma unroll
            for (int j4 = 0; j4 < 4; ++j4) {
                u32 u = ((const u32*)&v)[j4];
                a8[2*j4]   += bflo(u) * f;
                a8[2*j4+1] += bfhi(u) * f;
            }
        }
        #pragma unroll
        for (int j = 0; j < 8; ++j) {
            int c = ck*8 + j;
            trans[c][px ^ (c & 31)] = a8[j] + emb[c];
        }
    }
    __syncthreads();
    for (int it = 0; it < 32; ++it) {
        int c = (tid >> 5) + it*8, px = tid & 31;
        int idx = c*HWSZ + p0 + px;
        out[idx] = cur[idx] + 0.5f * trans[c][px ^ (c & 31)];
    }
}

// ---------------------------------------------------------------------------
extern "C" void kernel_launch(void* const* d_in, const int* in_sizes, int n_in,
                              void* d_out, int out_size, void* d_ws, size_t ws_size,
                              hipStream_t stream)
{
    const float* cur = (const float*)d_in[0];
    const float* nbr = (const float*)d_in[1];
    const float* cd  = (const float*)d_in[2];
    const float* aw  = (const float*)d_in[3];
    const float* ab  = (const float*)d_in[4];
    const float* ow  = (const float*)d_in[5];
    const float* ob  = (const float*)d_in[6];
    const float* g1w = (const float*)d_in[7];
    const float* g1b = (const float*)d_in[8];
    const float* g2w = (const float*)d_in[9];
    const float* g2b = (const float*)d_in[10];
    const float* ew  = (const float*)d_in[11];
    const float* eb  = (const float*)d_in[12];
    float* out = (float*)d_out;
    float* ws  = (float*)d_ws;

    float* offs = ws;                          // 1,327,104 f
    float* gbuf = offs + 1327104;              // 73,728 f
    float* emb  = gbuf + 73728;                // 256 f
    u16* nbrh = (u16*)(emb + 256);             // 8 * PLANE
    u16* curh = nbrh + (size_t)NN*PLANE;       // PLANE
    u16* alig = curh + PLANE;                  // 8 * PLANE (NHWC)
    u16* wpO  = alig + (size_t)NN*PLANE;       // 32*4608
    u16* wpG  = wpO + 147456;                  // 128*4608
    u16* wpA  = wpG + 589824;                  // 256*2304

    k_emb_sum<<<dim3(1), dim3(256), 0, stream>>>(cd, ew, eb, emb);
    k_to_nhwc<<<dim3(48, 8), dim3(256), 0, stream>>>(nbr, nbrh);
    k_to_nhwc<<<dim3(48, 1), dim3(256), 0, stream>>>(cur, curh);
    k_pack_w<<<dim3((32*4608 + 255)/256), dim3(256), 0, stream>>>(ow, wpO, 18, 32, 512);
    k_pack_w<<<dim3((128*4608 + 255)/256), dim3(256), 0, stream>>>(g1w, wpG, 128, 128, 512);
    k_pack_w<<<dim3((256*2304 + 255)/256), dim3(256), 0, stream>>>(aw, wpA, 256, 256, 256);

    // offset conv: concat(nbr_n, cur) -> 18 ch (padded to 32), XCD-pinned n
    k_conv_nhwc<1, 0><<<dim3(8, 36), dim3(512), 0, stream>>>(
        nbrh, (long)PLANE, curh, 0L, wpO, ob, nullptr, nullptr, offs);
    // deformable conv -> alig (NHWC bf16), XCD-pinned n
    k_deform_nhwc<<<dim3(8, 144), dim3(256), 0, stream>>>(nbrh, offs, wpA, ab, alig);
    // gate: concat(cur, alig_n) -> 128 -> relu -> 1x1 -> sigmoid, XCD-pinned n
    k_conv_nhwc<4, 1><<<dim3(8, 36), dim3(512), 0, stream>>>(
        curh, 0L, alig, (long)PLANE, wpG, g1b, g2w, g2b, gbuf);
    // softmax + fuse + residual
    k_fuse_nhwc<<<dim3(288), dim3(256), 0, stream>>>(cur, alig, gbuf, emb, out);
}